// Round 7
// baseline (1465.169 us; speedup 1.0000x reference)
//
#include <hip/hip_runtime.h>

// Problem constants: BATCH=16, N=128, D=128, N_STEPS=5, EPS=1e-10
#define EPSF 1e-10f

// ============================ K1: Cayley bases ============================
// M = I + A, A = L - L^T. Symmetric part of M is I (SPD) => unpivoted
// Gauss-Jordan is stable (all pivots >= 1). U = 2*M^{-1} - I.
// LDS layout: float4 (i, j4) stored at f4 index i*32 + (j4 ^ (i & 31)).
// Lane map: row i = wave*16 + (lane&15), chunk h = lane>>4 (4 threads/row,
// 8 float4 each). Each 8-lane beat hits 8 distinct rows -> swizzled
// addresses span all 8 bank groups -> conflict-free b128.
// SCRATCH FIX (r5): no runtime component indexing into register float4
// (Rule #20) -- branchless per-component selects only.
#define SWZ4(i, j4) ((i) * 32 + ((j4) ^ ((i) & 31)))
#define SWZF(i, j) (SWZ4((i), (j) >> 2) * 4 + ((j) & 3))

__global__ __launch_bounds__(512, 2) void k_cayley(const float* __restrict__ L,
                                                   float* __restrict__ bases) {
  extern __shared__ float4 M4[];  // 4096 float4 = 64 KB
  float* Mf = (float*)M4;
  const int n = blockIdx.x, t = threadIdx.x;
  const float* Ln = L + n * 16384;
  // load linear -> swizzled (coalesced global reads)
  for (int f = t; f < 4096; f += 512) {
    int i = f >> 5, j4 = f & 31;
    M4[SWZ4(i, j4)] = ((const float4*)Ln)[f];
  }
  __syncthreads();
  // antisymmetrize in place + unit diagonal (pair (i<j) owned by one thread)
  for (int f = t; f < 16384; f += 512) {
    int i = f >> 7, j = f & 127;
    if (i < j) {
      int a = SWZF(i, j), b = SWZF(j, i);
      float va = Mf[a], vb = Mf[b];
      Mf[a] = va - vb;
      Mf[b] = vb - va;
    } else if (i == j) {
      Mf[SWZF(i, i)] = 1.0f;
    }
  }
  __syncthreads();
  const int lane = t & 63, wva = t >> 6;
  const int i = wva * 16 + (lane & 15);  // row owned by this thread
  const int h = lane >> 4;               // which 8-float4 chunk of the row
  for (int k = 0; k < 128; ++k) {
    // ---- phase A: cross-thread reads only (pivot, multiplier, row k)
    float pivinv = 1.0f / Mf[SWZF(k, k)];   // broadcast
    float m = Mf[SWZF(i, k)];               // column read, conflict-spread
    float4 rk[8];
    #pragma unroll
    for (int u = 0; u < 8; ++u) rk[u] = M4[SWZ4(k, h * 8 + u)];  // bcast/beat
    __syncthreads();
    // ---- phase B: stream own row slice (self-owned: no cross-thread race)
    const int kj4 = k >> 2;  // float4 index of pivot column
    const int kc  = k & 3;   // component within it
    float coef = m * pivinv;
    if (i == k) {
      #pragma unroll
      for (int u = 0; u < 8; ++u) {
        int jj = h * 8 + u;
        float4 v = rk[u];
        v.x *= pivinv; v.y *= pivinv; v.z *= pivinv; v.w *= pivinv;
        if (jj == kj4) {  // branchless component patch (no dynamic indexing)
          v.x = (kc == 0) ? pivinv : v.x;
          v.y = (kc == 1) ? pivinv : v.y;
          v.z = (kc == 2) ? pivinv : v.z;
          v.w = (kc == 3) ? pivinv : v.w;
        }
        M4[SWZ4(k, jj)] = v;
      }
    } else {
      #pragma unroll
      for (int u = 0; u < 8; ++u) {
        int jj = h * 8 + u;
        float4 av = M4[SWZ4(i, jj)];  // streamed, not preloaded (no spill)
        float4 r = rk[u];
        av.x -= coef * r.x; av.y -= coef * r.y;
        av.z -= coef * r.z; av.w -= coef * r.w;
        if (jj == kj4) {  // branchless component patch (no dynamic indexing)
          av.x = (kc == 0) ? -coef : av.x;
          av.y = (kc == 1) ? -coef : av.y;
          av.z = (kc == 2) ? -coef : av.z;
          av.w = (kc == 3) ? -coef : av.w;
        }
        M4[SWZ4(i, jj)] = av;
      }
    }
    __syncthreads();
  }
  // write U = 2*Minv - I (coalesced global writes)
  for (int f = t; f < 16384; f += 512) {
    int ii = f >> 7, j = f & 127;
    float v = Mf[SWZF(ii, j)];
    bases[n * 16384 + f] = 2.0f * v - ((ii == j) ? 1.0f : 0.0f);
  }
}

// ============================ K2a: Gram of flattened bases ============================
__global__ __launch_bounds__(256) void k_gram(const float* __restrict__ bases,
                                              float* __restrict__ G) {
  const int i = blockIdx.x, t = threadIdx.x;
  __shared__ float redb[4];
  float4 ai[16];
  const float4* Bi = (const float4*)(bases + i * 16384);
  #pragma unroll
  for (int u = 0; u < 16; ++u) ai[u] = Bi[t + 256 * u];
  for (int j = 0; j < 128; ++j) {
    const float4* Bj = (const float4*)(bases + j * 16384);
    float acc = 0.f;
    #pragma unroll
    for (int u = 0; u < 16; ++u) {
      float4 b = Bj[t + 256 * u];
      acc += ai[u].x * b.x + ai[u].y * b.y + ai[u].z * b.z + ai[u].w * b.w;
    }
    for (int s = 32; s > 0; s >>= 1) acc += __shfl_down(acc, s);
    if ((t & 63) == 0) redb[t >> 6] = acc;
    __syncthreads();
    if (t == 0) G[i * 128 + j] = redb[0] + redb[1] + redb[2] + redb[3];
    __syncthreads();
  }
}

// ============================ K2b: tension + softmax + mask ============================
__global__ __launch_bounds__(128) void k_wsoft(const float* __restrict__ G,
                                               const float* __restrict__ temp_p,
                                               float* __restrict__ w,
                                               float* __restrict__ tension_out) {
  const int i = blockIdx.x, t = threadIdx.x;  // t = j
  __shared__ float rr[2], r2[2];
  float temp = fmaxf(fabsf(*temp_p), 0.01f);
  float gii = G[i * 128 + i], gjj = G[t * 128 + t], gij = G[i * 128 + t];
  float ten = sqrtf(fmaxf(gii + gjj - 2.0f * gij, 0.0f) + 1e-8f);
  tension_out[i * 128 + t] = ten;
  float logit = -ten / temp;
  float m = logit;
  for (int s = 32; s > 0; s >>= 1) m = fmaxf(m, __shfl_xor(m, s));
  if ((t & 63) == 0) rr[t >> 6] = m;
  __syncthreads();
  float mx = fmaxf(rr[0], rr[1]);
  float ex = expf(logit - mx);
  float ssum = ex;
  for (int s = 32; s > 0; s >>= 1) ssum += __shfl_xor(ssum, s);
  if ((t & 63) == 0) r2[t >> 6] = ssum;
  __syncthreads();
  float tot = r2[0] + r2[1];
  float wv = ex / tot;
  if (t == i) wv = 0.0f;
  w[i * 128 + t] = wv;
}

// ============================ K3: measurements + initial norms ============================
__global__ __launch_bounds__(128) void k_meas(const float* __restrict__ x,
                                              const float* __restrict__ bases,
                                              float* __restrict__ meas_out,
                                              float* __restrict__ state0,
                                              float* __restrict__ norms0) {
  const int n = blockIdx.x, t = threadIdx.x;  // t = k
  __shared__ float xs[2048];
  __shared__ float red[2];
  for (int f = t; f < 2048; f += 128) xs[f] = x[f];
  __syncthreads();
  float acc[16];
  #pragma unroll
  for (int b = 0; b < 16; ++b) acc[b] = 0.f;
  for (int d = 0; d < 128; ++d) {
    float u = bases[n * 16384 + d * 128 + t];  // coalesced over t
    #pragma unroll
    for (int b = 0; b < 16; ++b) acc[b] += xs[b * 128 + d] * u;
  }
  for (int b = 0; b < 16; ++b) {
    meas_out[(b * 128 + n) * 128 + t] = acc[b];
    state0[(b * 128 + n) * 128 + t] = acc[b];
  }
  for (int b = 0; b < 16; ++b) {
    float v = acc[b] * acc[b];
    for (int s = 32; s > 0; s >>= 1) v += __shfl_down(v, s);
    if ((t & 63) == 0) red[t >> 6] = v;
    __syncthreads();
    if (t == 0) norms0[b * 128 + n] = sqrtf(red[0] + red[1]);
    __syncthreads();
  }
}

// ============================ K4: one interaction step ============================
__global__ __launch_bounds__(128) void k_step(const float* __restrict__ src,
                                              float* __restrict__ dst,
                                              const float* __restrict__ w,
                                              const float* __restrict__ norms_in,
                                              float* __restrict__ norms_out,
                                              const float* __restrict__ tgt_p,
                                              const float* __restrict__ step_p) {
  const int b = blockIdx.x >> 7, n = blockIdx.x & 127, t = threadIdx.x;
  __shared__ float sn[128];
  __shared__ float chunk[32][129];
  __shared__ float red[2][32][2];
  __shared__ float cbuf[32];
  __shared__ float red2[2];
  const float target = *tgt_p;
  const float step = fminf(fmaxf(fabsf(*step_p), 0.001f), 0.5f);
  const float* srcb = src + b * 16384;
  float x_d = srcb[n * 128 + t];
  sn[t] = x_d;
  float norm_n = norms_in[b * 128 + n];
  float f_d = 0.0f;
  __syncthreads();
  for (int c0 = 0; c0 < 128; c0 += 32) {
    for (int f = t; f < 4096; f += 128) {
      int row = f >> 7, col = f & 127;
      chunk[row][col] = srcb[(c0 + row) * 128 + col];
    }
    __syncthreads();
    int m = t & 31, q = t >> 5;
    float dp = 0.f, sp = 0.f;
    const float* cr = &chunk[m][0];
    #pragma unroll
    for (int i2 = 0; i2 < 32; ++i2) {
      int dd = q * 32 + i2;
      float smv = cr[dd];
      float snd = sn[dd];
      dp += smv * snd;
      float df = snd - smv;
      sp += df * df;
    }
    dp += __shfl_xor(dp, 32);
    sp += __shfl_xor(sp, 32);
    int wave = t >> 6;
    if ((t & 63) < 32) { red[wave][m][0] = dp; red[wave][m][1] = sp; }
    __syncthreads();
    if (t < 32) {
      float dot = red[0][t][0] + red[1][t][0];
      float sq  = red[0][t][1] + red[1][t][1];
      int mm = c0 + t;
      float norm_m = norms_in[b * 128 + mm];
      float wnm = w[n * 128 + mm];
      float cs = dot / ((norm_n + EPSF) * (norm_m + EPSF));
      float fm = (cs - target) * wnm;
      cbuf[t] = fm / (sqrtf(fmaxf(sq, 0.0f)) + EPSF);
    }
    __syncthreads();
    #pragma unroll
    for (int mi = 0; mi < 32; ++mi) f_d += cbuf[mi] * (x_d - chunk[mi][t]);
    __syncthreads();
  }
  float nv = x_d + step * f_d;
  dst[(b * 128 + n) * 128 + t] = nv;
  float v = nv * nv;
  for (int s = 32; s > 0; s >>= 1) v += __shfl_down(v, s);
  if ((t & 63) == 0) red2[t >> 6] = v;
  __syncthreads();
  if (t == 0) norms_out[b * 128 + n] = sqrtf(red2[0] + red2[1]);
}

// ============================ K5: expressions ============================
__global__ __launch_bounds__(128) void k_expr(const float* __restrict__ eq,
                                              const float* __restrict__ bases,
                                              float* __restrict__ expr_out) {
  const int n = blockIdx.x, t = threadIdx.x;  // t = k
  __shared__ __align__(16) float es[16][128];
  for (int f = t; f < 2048; f += 128)
    es[f >> 7][f & 127] = eq[((f >> 7) * 128 + n) * 128 + (f & 127)];
  __syncthreads();
  float acc[16];
  #pragma unroll
  for (int b = 0; b < 16; ++b) acc[b] = 0.f;
  const float4* U = (const float4*)(bases + n * 16384 + t * 128);
  for (int d4 = 0; d4 < 32; ++d4) {
    float4 u = U[d4];
    #pragma unroll
    for (int b = 0; b < 16; ++b) {
      float4 e4 = ((const float4*)&es[b][0])[d4];
      acc[b] += u.x * e4.x + u.y * e4.y + u.z * e4.z + u.w * e4.w;
    }
  }
  for (int b = 0; b < 16; ++b) expr_out[(b * 128 + n) * 128 + t] = acc[b];
}

// ============================ K5b: output_avg ============================
__global__ __launch_bounds__(128) void k_avg(const float* __restrict__ expr,
                                             float* __restrict__ avg) {
  const int b = blockIdx.x, t = threadIdx.x;
  float s = 0.f;
  for (int n = 0; n < 128; ++n) s += expr[(b * 128 + n) * 128 + t];
  avg[b * 128 + t] = s * (1.0f / 128.0f);
}

// ============================ K6: rho ============================
__global__ __launch_bounds__(256) void k_rho(const float* __restrict__ eq,
                                             const float* __restrict__ norms,
                                             float* __restrict__ rho) {
  const int b = blockIdx.x >> 3, dt = blockIdx.x & 7;
  const int t = threadIdx.x;
  __shared__ float ch[32][129];
  int e = t & 127, dl = t >> 7;
  float acc[8];
  #pragma unroll
  for (int o = 0; o < 8; ++o) acc[o] = 0.f;
  for (int c0 = 0; c0 < 128; c0 += 32) {
    for (int f = t; f < 4096; f += 256) {
      int row = f >> 7, col = f & 127;
      int nn = c0 + row;
      float inv = 1.0f / (norms[b * 128 + nn] + EPSF);
      ch[row][col] = eq[(b * 128 + nn) * 128 + col] * inv;
    }
    __syncthreads();
    for (int nn = 0; nn < 32; ++nn) {
      float me = ch[nn][e];
      #pragma unroll
      for (int o = 0; o < 8; ++o) {
        int d = dt * 16 + dl + o * 2;
        acc[o] += ch[nn][d] * me;
      }
    }
    __syncthreads();
  }
  for (int o = 0; o < 8; ++o) {
    int d = dt * 16 + dl + o * 2;
    rho[(b * 128 + d) * 128 + e] = acc[o] * (1.0f / 128.0f);
  }
}

// ============================ K7: Householder tridiagonalization ============================
// SINGLE WAVE (64 threads, rows t and t+64). All reductions via DPP
// (row_shr 1/2/4/8 + row_bcast15/31 + readlane 63: VALU-latency, ~50cyc vs
// ~700cyc for 6-deep ds_bpermute shfl chains). Next Householder column is
// extracted IN REGISTERS during the rank-2 update (branchless component
// select) -- no column read, no x0 LDS round trip (runtime readlane).
// 2 cheap single-wave barriers per step. Rows i<=k are FROZEN (not updated)
// so stale data stays finite; their p-values are garbage-but-finite and only
// ever multiply into never-read-again columns j<=k.
#define TSW(i, j4) ((i) * 32 + ((j4) ^ ((i) & 31)))
#define AEL(i, j) (Af[TSW((i), (j) >> 2) * 4 + ((j) & 3)])

__device__ __forceinline__ float dpp_red_sum64(float x) {
  // canonical GCN wave64 sum: accumulate into lane 63, broadcast via readlane
  x += __int_as_float(__builtin_amdgcn_update_dpp(0, __float_as_int(x), 0x111, 0xf, 0xf, true));
  x += __int_as_float(__builtin_amdgcn_update_dpp(0, __float_as_int(x), 0x112, 0xf, 0xf, true));
  x += __int_as_float(__builtin_amdgcn_update_dpp(0, __float_as_int(x), 0x114, 0xf, 0xe, true));
  x += __int_as_float(__builtin_amdgcn_update_dpp(0, __float_as_int(x), 0x118, 0xf, 0xc, true));
  x += __int_as_float(__builtin_amdgcn_update_dpp(0, __float_as_int(x), 0x142, 0xa, 0xf, true));
  x += __int_as_float(__builtin_amdgcn_update_dpp(0, __float_as_int(x), 0x143, 0xc, 0xf, true));
  return __int_as_float(__builtin_amdgcn_readlane(__float_as_int(x), 63));
}

__device__ __forceinline__ float f4sel(float4 a, int cc) {
  float r = (cc == 0) ? a.x : a.y;
  r = (cc == 2) ? a.z : r;
  r = (cc == 3) ? a.w : r;
  return r;
}

__global__ __launch_bounds__(64) void k_tridiag(const float* __restrict__ rho,
                                                float* __restrict__ dvec_g,
                                                float* __restrict__ evec_g) {
  extern __shared__ float sm[];
  float4* A4  = (float4*)sm;        // 4096 float4 = 64 KB
  float*  Af  = sm;
  float* vbuf = sm + 16384;         // 128
  float* pbuf = vbuf + 128;         // 128
  float* dvl  = pbuf + 128;         // 128
  float* evl  = dvl + 128;          // 128
  const int bb = blockIdx.x, t = threadIdx.x;  // 64 threads
  const int r0 = t, r1 = t + 64;
  const float* R = rho + bb * 16384;
  for (int f = t; f < 4096; f += 64)
    A4[TSW(f >> 5, f & 31)] = ((const float4*)R)[f];
  __syncthreads();
  float cA = AEL(r0, 0), cB = AEL(r1, 0);   // current column (k) in regs
  const float4* v4 = (const float4*)vbuf;
  const float4* p4 = (const float4*)pbuf;
  for (int k = 0; k < 126; ++k) {
    const bool mA = (r0 > k), mB = (r1 > k);
    // ---- sigma^2 (DPP), x0 (readlane), dv[k]
    float s2 = (mA ? cA * cA : 0.f) + (mB ? cB * cB : 0.f);
    s2 = dpp_red_sum64(s2);
    const int xr = k + 1;
    float x0 = (xr < 64)
        ? __int_as_float(__builtin_amdgcn_readlane(__float_as_int(cA), xr))
        : __int_as_float(__builtin_amdgcn_readlane(__float_as_int(cB), xr - 64));
    if (k < 64) { if (t == k) dvl[k] = cA; }
    else        { if (t == k - 64) dvl[k] = cB; }
    // ---- alpha/beta/w0 (uniform, all lanes)
    const bool skip = (s2 < 1e-30f);
    float sig = sqrtf(s2);
    float alpha = (x0 >= 0.f) ? -sig : sig;
    if (skip) alpha = 0.f;
    float beta = skip ? 0.f : 1.f / (s2 - alpha * x0);
    float w0 = x0 - alpha;
    if (t == 0) evl[k] = alpha;
    // ---- publish v (zeros below k+1)
    float vvA = mA ? ((r0 == k + 1) ? w0 : cA) : 0.f;
    float vvB = mB ? ((r1 == k + 1) ? w0 : cB) : 0.f;
    vbuf[r0] = vvA;
    vbuf[r1] = vvB;
    __syncthreads();  // S1
    // ---- matvec p = beta * A v  (frozen rows produce finite garbage, ok)
    const int j4min = (k + 1) >> 2;
    float pA = 0.f, pB = 0.f;
    if (k < 63) {  // uniform: some r0 rows still active
      for (int j4 = j4min; j4 < 32; ++j4) {
        float4 v = v4[j4];
        float4 a0 = A4[TSW(r0, j4)];
        float4 a1 = A4[TSW(r1, j4)];
        pA += a0.x * v.x + a0.y * v.y + a0.z * v.z + a0.w * v.w;
        pB += a1.x * v.x + a1.y * v.y + a1.z * v.z + a1.w * v.w;
      }
    } else {
      for (int j4 = j4min; j4 < 32; ++j4) {
        float4 v = v4[j4];
        float4 a1 = A4[TSW(r1, j4)];
        pB += a1.x * v.x + a1.y * v.y + a1.z * v.z + a1.w * v.w;
      }
    }
    pA *= beta; pB *= beta;
    pbuf[r0] = pA;
    pbuf[r1] = pB;
    // ---- K (DPP; v masks frozen-row garbage with exact zeros)
    float K = dpp_red_sum64(vvA * pA + vvB * pB) * beta * 0.5f;
    __syncthreads();  // S2
    // ---- rank-2 update A -= v q^T + q v^T, extract column k+1 on the fly
    const int j4c = (k + 1) >> 2, cc = (k + 1) & 3;
    float qA = pA - K * vvA, qB = pB - K * vvB;
    if (k < 63) {
      for (int j4 = j4min; j4 < 32; ++j4) {
        float4 v = v4[j4], p = p4[j4];
        float4 q;
        q.x = p.x - K * v.x; q.y = p.y - K * v.y;
        q.z = p.z - K * v.z; q.w = p.w - K * v.w;
        if (mA) {
          float4 a = A4[TSW(r0, j4)];
          a.x -= vvA * q.x + qA * v.x; a.y -= vvA * q.y + qA * v.y;
          a.z -= vvA * q.z + qA * v.z; a.w -= vvA * q.w + qA * v.w;
          A4[TSW(r0, j4)] = a;
          if (j4 == j4c) cA = f4sel(a, cc);
        }
        {  // mB all-true here (r1 >= 64 > k)
          float4 a = A4[TSW(r1, j4)];
          a.x -= vvB * q.x + qB * v.x; a.y -= vvB * q.y + qB * v.y;
          a.z -= vvB * q.z + qB * v.z; a.w -= vvB * q.w + qB * v.w;
          A4[TSW(r1, j4)] = a;
          if (j4 == j4c) cB = f4sel(a, cc);
        }
      }
    } else {
      for (int j4 = j4min; j4 < 32; ++j4) {
        float4 v = v4[j4], p = p4[j4];
        float4 q;
        q.x = p.x - K * v.x; q.y = p.y - K * v.y;
        q.z = p.z - K * v.z; q.w = p.w - K * v.w;
        if (mB) {
          float4 a = A4[TSW(r1, j4)];
          a.x -= vvB * q.x + qB * v.x; a.y -= vvB * q.y + qB * v.y;
          a.z -= vvB * q.z + qB * v.z; a.w -= vvB * q.w + qB * v.w;
          A4[TSW(r1, j4)] = a;
          if (j4 == j4c) cB = f4sel(a, cc);
        }
      }
    }
    __syncthreads();  // S3 (A stable before next matvec / final reads)
  }
  // after k=125: c regs hold column 126
  if (t == 62) dvl[126] = cB;                       // A[126][126]
  if (t == 63) {
    evl[126] = cB;                                  // A[127][126]
    dvl[127] = AEL(127, 127);
    evl[127] = 0.0f;
  }
  __syncthreads();
  dvec_g[bb * 128 + t] = dvl[t];
  dvec_g[bb * 128 + 64 + t] = dvl[64 + t];
  evec_g[bb * 128 + t] = evl[t];
  evec_g[bb * 128 + 64 + t] = evl[64 + t];
}

// ============================ K8: bisection eigenvalues + normalize ============================
__global__ __launch_bounds__(128) void k_bisect(const float* __restrict__ dvec_g,
                                                const float* __restrict__ evec_g,
                                                float* __restrict__ dist_out) {
  const int bb = blockIdx.x, t = threadIdx.x;
  __shared__ float ds[128], e2s[128], eabs[128];
  __shared__ float rr[2];
  ds[t] = dvec_g[bb * 128 + t];
  float e = evec_g[bb * 128 + t];
  e2s[t] = e * e;
  eabs[t] = fabsf(e);
  __syncthreads();
  float lo = 1e30f, hi = -1e30f;
  for (int ii = 0; ii < 128; ++ii) {
    float r = (ii > 0 ? eabs[ii - 1] : 0.0f) + (ii < 127 ? eabs[ii] : 0.0f);
    lo = fminf(lo, ds[ii] - r);
    hi = fmaxf(hi, ds[ii] + r);
  }
  for (int it = 0; it < 40; ++it) {
    float mid = 0.5f * (lo + hi);
    int cnt = 0;
    float q = ds[0] - mid;
    if (q < 0.0f) cnt++;
    for (int ii = 1; ii < 128; ++ii) {
      float denom = q;
      if (fabsf(denom) < 1e-25f) denom = (denom < 0.0f) ? -1e-25f : 1e-25f;
      q = (ds[ii] - mid) - __fdividef(e2s[ii - 1], denom);
      if (q < 0.0f) cnt++;
    }
    if (cnt <= t) lo = mid; else hi = mid;
  }
  float lam = 0.5f * (lo + hi);
  float evc = fmaxf(lam, 1e-12f);
  float ssum = evc;
  for (int s = 32; s > 0; s >>= 1) ssum += __shfl_xor(ssum, s);
  if ((t & 63) == 0) rr[t >> 6] = ssum;
  __syncthreads();
  float tot = rr[0] + rr[1];
  dist_out[bb * 128 + t] = evc / tot;
}

// ============================ launch ============================
extern "C" void kernel_launch(void* const* d_in, const int* in_sizes, int n_in,
                              void* d_out, int out_size, void* d_ws, size_t ws_size,
                              hipStream_t stream) {
  const float* x      = (const float*)d_in[0];
  const float* L      = (const float*)d_in[1];
  const float* temp_p = (const float*)d_in[2];
  const float* tgt_p  = (const float*)d_in[3];
  const float* step_p = (const float*)d_in[4];
  float* out = (float*)d_out;
  float* ws  = (float*)d_ws;

  float* bases = ws;                    // 2097152
  float* G     = bases + 2097152;       // 16384
  float* w     = G + 16384;             // 16384
  float* s0    = w + 16384;             // 262144
  float* s1    = s0 + 262144;           // 262144
  float* n0    = s1 + 262144;           // 2048
  float* n1    = n0 + 2048;             // 2048
  float* dv    = n1 + 2048;             // 2048
  float* ev    = dv + 2048;             // 2048

  float* o_avg  = out;                  // 2048
  float* o_dist = out + 2048;           // 2048
  float* o_rho  = out + 4096;           // 262144
  float* o_meas = out + 266240;         // 262144
  float* o_eq   = out + 528384;         // 262144
  float* o_expr = out + 790528;         // 262144
  float* o_ten  = out + 1052672;        // 16384

  hipFuncSetAttribute((const void*)k_cayley,
                      hipFuncAttributeMaxDynamicSharedMemorySize, 65536);
  hipFuncSetAttribute((const void*)k_tridiag,
                      hipFuncAttributeMaxDynamicSharedMemorySize, 67584);

  k_cayley<<<128, 512, 65536, stream>>>(L, bases);
  k_gram<<<128, 256, 0, stream>>>(bases, G);
  k_wsoft<<<128, 128, 0, stream>>>(G, temp_p, w, o_ten);
  k_meas<<<128, 128, 0, stream>>>(x, bases, o_meas, s0, n0);
  k_step<<<2048, 128, 0, stream>>>(s0, s1, w, n0, n1, tgt_p, step_p);
  k_step<<<2048, 128, 0, stream>>>(s1, s0, w, n1, n0, tgt_p, step_p);
  k_step<<<2048, 128, 0, stream>>>(s0, s1, w, n0, n1, tgt_p, step_p);
  k_step<<<2048, 128, 0, stream>>>(s1, s0, w, n1, n0, tgt_p, step_p);
  k_step<<<2048, 128, 0, stream>>>(s0, o_eq, w, n0, n1, tgt_p, step_p);
  k_expr<<<128, 128, 0, stream>>>(o_eq, bases, o_expr);
  k_avg<<<16, 128, 0, stream>>>(o_expr, o_avg);
  k_rho<<<128, 256, 0, stream>>>(o_eq, n1, o_rho);
  k_tridiag<<<16, 64, 67584, stream>>>(o_rho, dv, ev);
  k_bisect<<<16, 128, 0, stream>>>(dv, ev, o_dist);
}

// Round 8
// 1333.271 us; speedup vs baseline: 1.0989x; 1.0989x over previous
//
#include <hip/hip_runtime.h>

// Problem constants: BATCH=16, N=128, D=128, N_STEPS=5, EPS=1e-10
#define EPSF 1e-10f

// ============================ K1: Cayley bases ============================
// M = I + A, A = L - L^T. Symmetric part of M is I (SPD) => unpivoted
// Gauss-Jordan is stable (all pivots >= 1). U = 2*M^{-1} - I.
// LDS layout: float4 (i, j4) stored at f4 index i*32 + (j4 ^ (i & 31)).
// Lane map: row i = wave*16 + (lane&15), chunk h = lane>>4 (4 threads/row,
// 8 float4 each). Each 8-lane beat hits 8 distinct rows -> swizzled
// addresses span all 8 bank groups -> conflict-free b128.
// SCRATCH FIX (r5): no runtime component indexing into register float4
// (Rule #20) -- branchless per-component selects only.
#define SWZ4(i, j4) ((i) * 32 + ((j4) ^ ((i) & 31)))
#define SWZF(i, j) (SWZ4((i), (j) >> 2) * 4 + ((j) & 3))

__global__ __launch_bounds__(512, 2) void k_cayley(const float* __restrict__ L,
                                                   float* __restrict__ bases) {
  extern __shared__ float4 M4[];  // 4096 float4 = 64 KB
  float* Mf = (float*)M4;
  const int n = blockIdx.x, t = threadIdx.x;
  const float* Ln = L + n * 16384;
  // load linear -> swizzled (coalesced global reads)
  for (int f = t; f < 4096; f += 512) {
    int i = f >> 5, j4 = f & 31;
    M4[SWZ4(i, j4)] = ((const float4*)Ln)[f];
  }
  __syncthreads();
  // antisymmetrize in place + unit diagonal (pair (i<j) owned by one thread)
  for (int f = t; f < 16384; f += 512) {
    int i = f >> 7, j = f & 127;
    if (i < j) {
      int a = SWZF(i, j), b = SWZF(j, i);
      float va = Mf[a], vb = Mf[b];
      Mf[a] = va - vb;
      Mf[b] = vb - va;
    } else if (i == j) {
      Mf[SWZF(i, i)] = 1.0f;
    }
  }
  __syncthreads();
  const int lane = t & 63, wva = t >> 6;
  const int i = wva * 16 + (lane & 15);  // row owned by this thread
  const int h = lane >> 4;               // which 8-float4 chunk of the row
  for (int k = 0; k < 128; ++k) {
    // ---- phase A: cross-thread reads only (pivot, multiplier, row k)
    float pivinv = 1.0f / Mf[SWZF(k, k)];   // broadcast
    float m = Mf[SWZF(i, k)];               // column read, conflict-spread
    float4 rk[8];
    #pragma unroll
    for (int u = 0; u < 8; ++u) rk[u] = M4[SWZ4(k, h * 8 + u)];  // bcast/beat
    __syncthreads();
    // ---- phase B: stream own row slice (self-owned: no cross-thread race)
    const int kj4 = k >> 2;  // float4 index of pivot column
    const int kc  = k & 3;   // component within it
    float coef = m * pivinv;
    if (i == k) {
      #pragma unroll
      for (int u = 0; u < 8; ++u) {
        int jj = h * 8 + u;
        float4 v = rk[u];
        v.x *= pivinv; v.y *= pivinv; v.z *= pivinv; v.w *= pivinv;
        if (jj == kj4) {  // branchless component patch (no dynamic indexing)
          v.x = (kc == 0) ? pivinv : v.x;
          v.y = (kc == 1) ? pivinv : v.y;
          v.z = (kc == 2) ? pivinv : v.z;
          v.w = (kc == 3) ? pivinv : v.w;
        }
        M4[SWZ4(k, jj)] = v;
      }
    } else {
      #pragma unroll
      for (int u = 0; u < 8; ++u) {
        int jj = h * 8 + u;
        float4 av = M4[SWZ4(i, jj)];  // streamed, not preloaded (no spill)
        float4 r = rk[u];
        av.x -= coef * r.x; av.y -= coef * r.y;
        av.z -= coef * r.z; av.w -= coef * r.w;
        if (jj == kj4) {  // branchless component patch (no dynamic indexing)
          av.x = (kc == 0) ? -coef : av.x;
          av.y = (kc == 1) ? -coef : av.y;
          av.z = (kc == 2) ? -coef : av.z;
          av.w = (kc == 3) ? -coef : av.w;
        }
        M4[SWZ4(i, jj)] = av;
      }
    }
    __syncthreads();
  }
  // write U = 2*Minv - I (coalesced global writes)
  for (int f = t; f < 16384; f += 512) {
    int ii = f >> 7, j = f & 127;
    float v = Mf[SWZF(ii, j)];
    bases[n * 16384 + f] = 2.0f * v - ((ii == j) ? 1.0f : 0.0f);
  }
}

// ============================ K2a: Gram of flattened bases ============================
__global__ __launch_bounds__(256) void k_gram(const float* __restrict__ bases,
                                              float* __restrict__ G) {
  const int i = blockIdx.x, t = threadIdx.x;
  __shared__ float redb[4];
  float4 ai[16];
  const float4* Bi = (const float4*)(bases + i * 16384);
  #pragma unroll
  for (int u = 0; u < 16; ++u) ai[u] = Bi[t + 256 * u];
  for (int j = 0; j < 128; ++j) {
    const float4* Bj = (const float4*)(bases + j * 16384);
    float acc = 0.f;
    #pragma unroll
    for (int u = 0; u < 16; ++u) {
      float4 b = Bj[t + 256 * u];
      acc += ai[u].x * b.x + ai[u].y * b.y + ai[u].z * b.z + ai[u].w * b.w;
    }
    for (int s = 32; s > 0; s >>= 1) acc += __shfl_down(acc, s);
    if ((t & 63) == 0) redb[t >> 6] = acc;
    __syncthreads();
    if (t == 0) G[i * 128 + j] = redb[0] + redb[1] + redb[2] + redb[3];
    __syncthreads();
  }
}

// ============================ K2b: tension + softmax + mask ============================
__global__ __launch_bounds__(128) void k_wsoft(const float* __restrict__ G,
                                               const float* __restrict__ temp_p,
                                               float* __restrict__ w,
                                               float* __restrict__ tension_out) {
  const int i = blockIdx.x, t = threadIdx.x;  // t = j
  __shared__ float rr[2], r2[2];
  float temp = fmaxf(fabsf(*temp_p), 0.01f);
  float gii = G[i * 128 + i], gjj = G[t * 128 + t], gij = G[i * 128 + t];
  float ten = sqrtf(fmaxf(gii + gjj - 2.0f * gij, 0.0f) + 1e-8f);
  tension_out[i * 128 + t] = ten;
  float logit = -ten / temp;
  float m = logit;
  for (int s = 32; s > 0; s >>= 1) m = fmaxf(m, __shfl_xor(m, s));
  if ((t & 63) == 0) rr[t >> 6] = m;
  __syncthreads();
  float mx = fmaxf(rr[0], rr[1]);
  float ex = expf(logit - mx);
  float ssum = ex;
  for (int s = 32; s > 0; s >>= 1) ssum += __shfl_xor(ssum, s);
  if ((t & 63) == 0) r2[t >> 6] = ssum;
  __syncthreads();
  float tot = r2[0] + r2[1];
  float wv = ex / tot;
  if (t == i) wv = 0.0f;
  w[i * 128 + t] = wv;
}

// ============================ K3: measurements + initial norms ============================
__global__ __launch_bounds__(128) void k_meas(const float* __restrict__ x,
                                              const float* __restrict__ bases,
                                              float* __restrict__ meas_out,
                                              float* __restrict__ state0,
                                              float* __restrict__ norms0) {
  const int n = blockIdx.x, t = threadIdx.x;  // t = k
  __shared__ float xs[2048];
  __shared__ float red[2];
  for (int f = t; f < 2048; f += 128) xs[f] = x[f];
  __syncthreads();
  float acc[16];
  #pragma unroll
  for (int b = 0; b < 16; ++b) acc[b] = 0.f;
  for (int d = 0; d < 128; ++d) {
    float u = bases[n * 16384 + d * 128 + t];  // coalesced over t
    #pragma unroll
    for (int b = 0; b < 16; ++b) acc[b] += xs[b * 128 + d] * u;
  }
  for (int b = 0; b < 16; ++b) {
    meas_out[(b * 128 + n) * 128 + t] = acc[b];
    state0[(b * 128 + n) * 128 + t] = acc[b];
  }
  for (int b = 0; b < 16; ++b) {
    float v = acc[b] * acc[b];
    for (int s = 32; s > 0; s >>= 1) v += __shfl_down(v, s);
    if ((t & 63) == 0) red[t >> 6] = v;
    __syncthreads();
    if (t == 0) norms0[b * 128 + n] = sqrtf(red[0] + red[1]);
    __syncthreads();
  }
}

// ============================ K4: one interaction step ============================
__global__ __launch_bounds__(128) void k_step(const float* __restrict__ src,
                                              float* __restrict__ dst,
                                              const float* __restrict__ w,
                                              const float* __restrict__ norms_in,
                                              float* __restrict__ norms_out,
                                              const float* __restrict__ tgt_p,
                                              const float* __restrict__ step_p) {
  const int b = blockIdx.x >> 7, n = blockIdx.x & 127, t = threadIdx.x;
  __shared__ float sn[128];
  __shared__ float chunk[32][129];
  __shared__ float red[2][32][2];
  __shared__ float cbuf[32];
  __shared__ float red2[2];
  const float target = *tgt_p;
  const float step = fminf(fmaxf(fabsf(*step_p), 0.001f), 0.5f);
  const float* srcb = src + b * 16384;
  float x_d = srcb[n * 128 + t];
  sn[t] = x_d;
  float norm_n = norms_in[b * 128 + n];
  float f_d = 0.0f;
  __syncthreads();
  for (int c0 = 0; c0 < 128; c0 += 32) {
    for (int f = t; f < 4096; f += 128) {
      int row = f >> 7, col = f & 127;
      chunk[row][col] = srcb[(c0 + row) * 128 + col];
    }
    __syncthreads();
    int m = t & 31, q = t >> 5;
    float dp = 0.f, sp = 0.f;
    const float* cr = &chunk[m][0];
    #pragma unroll
    for (int i2 = 0; i2 < 32; ++i2) {
      int dd = q * 32 + i2;
      float smv = cr[dd];
      float snd = sn[dd];
      dp += smv * snd;
      float df = snd - smv;
      sp += df * df;
    }
    dp += __shfl_xor(dp, 32);
    sp += __shfl_xor(sp, 32);
    int wave = t >> 6;
    if ((t & 63) < 32) { red[wave][m][0] = dp; red[wave][m][1] = sp; }
    __syncthreads();
    if (t < 32) {
      float dot = red[0][t][0] + red[1][t][0];
      float sq  = red[0][t][1] + red[1][t][1];
      int mm = c0 + t;
      float norm_m = norms_in[b * 128 + mm];
      float wnm = w[n * 128 + mm];
      float cs = dot / ((norm_n + EPSF) * (norm_m + EPSF));
      float fm = (cs - target) * wnm;
      cbuf[t] = fm / (sqrtf(fmaxf(sq, 0.0f)) + EPSF);
    }
    __syncthreads();
    #pragma unroll
    for (int mi = 0; mi < 32; ++mi) f_d += cbuf[mi] * (x_d - chunk[mi][t]);
    __syncthreads();
  }
  float nv = x_d + step * f_d;
  dst[(b * 128 + n) * 128 + t] = nv;
  float v = nv * nv;
  for (int s = 32; s > 0; s >>= 1) v += __shfl_down(v, s);
  if ((t & 63) == 0) red2[t >> 6] = v;
  __syncthreads();
  if (t == 0) norms_out[b * 128 + n] = sqrtf(red2[0] + red2[1]);
}

// ============================ K5: expressions ============================
__global__ __launch_bounds__(128) void k_expr(const float* __restrict__ eq,
                                              const float* __restrict__ bases,
                                              float* __restrict__ expr_out) {
  const int n = blockIdx.x, t = threadIdx.x;  // t = k
  __shared__ __align__(16) float es[16][128];
  for (int f = t; f < 2048; f += 128)
    es[f >> 7][f & 127] = eq[((f >> 7) * 128 + n) * 128 + (f & 127)];
  __syncthreads();
  float acc[16];
  #pragma unroll
  for (int b = 0; b < 16; ++b) acc[b] = 0.f;
  const float4* U = (const float4*)(bases + n * 16384 + t * 128);
  for (int d4 = 0; d4 < 32; ++d4) {
    float4 u = U[d4];
    #pragma unroll
    for (int b = 0; b < 16; ++b) {
      float4 e4 = ((const float4*)&es[b][0])[d4];
      acc[b] += u.x * e4.x + u.y * e4.y + u.z * e4.z + u.w * e4.w;
    }
  }
  for (int b = 0; b < 16; ++b) expr_out[(b * 128 + n) * 128 + t] = acc[b];
}

// ============================ K5b: output_avg ============================
__global__ __launch_bounds__(128) void k_avg(const float* __restrict__ expr,
                                             float* __restrict__ avg) {
  const int b = blockIdx.x, t = threadIdx.x;
  float s = 0.f;
  for (int n = 0; n < 128; ++n) s += expr[(b * 128 + n) * 128 + t];
  avg[b * 128 + t] = s * (1.0f / 128.0f);
}

// ============================ K6: rho ============================
__global__ __launch_bounds__(256) void k_rho(const float* __restrict__ eq,
                                             const float* __restrict__ norms,
                                             float* __restrict__ rho) {
  const int b = blockIdx.x >> 3, dt = blockIdx.x & 7;
  const int t = threadIdx.x;
  __shared__ float ch[32][129];
  int e = t & 127, dl = t >> 7;
  float acc[8];
  #pragma unroll
  for (int o = 0; o < 8; ++o) acc[o] = 0.f;
  for (int c0 = 0; c0 < 128; c0 += 32) {
    for (int f = t; f < 4096; f += 256) {
      int row = f >> 7, col = f & 127;
      int nn = c0 + row;
      float inv = 1.0f / (norms[b * 128 + nn] + EPSF);
      ch[row][col] = eq[(b * 128 + nn) * 128 + col] * inv;
    }
    __syncthreads();
    for (int nn = 0; nn < 32; ++nn) {
      float me = ch[nn][e];
      #pragma unroll
      for (int o = 0; o < 8; ++o) {
        int d = dt * 16 + dl + o * 2;
        acc[o] += ch[nn][d] * me;
      }
    }
    __syncthreads();
  }
  for (int o = 0; o < 8; ++o) {
    int d = dt * 16 + dl + o * 2;
    rho[(b * 128 + d) * 128 + e] = acc[o] * (1.0f / 128.0f);
  }
}

// ============================ K7: Householder tridiagonalization ============================
// 128 threads (2 waves, 1 row/thread) + register column extraction + DPP
// reductions + ping-pong column buffer => 2 barriers/step, no column-read
// phase. sigma^2 / x0 / diag for step k+1 are produced during step k's
// update (per-thread extracted element -> DPP wave sums -> 2 LDS slots).
// Rows <= k frozen (finite stale data, never read again).
#define TSW(i, j4) ((i) * 32 + ((j4) ^ ((i) & 31)))
#define AEL(i, j) (Af[TSW((i), (j) >> 2) * 4 + ((j) & 3)])

__device__ __forceinline__ float dpp_red_sum64(float x) {
  // canonical GCN wave64 sum: accumulate into lane 63, broadcast via readlane
  x += __int_as_float(__builtin_amdgcn_update_dpp(0, __float_as_int(x), 0x111, 0xf, 0xf, true));
  x += __int_as_float(__builtin_amdgcn_update_dpp(0, __float_as_int(x), 0x112, 0xf, 0xf, true));
  x += __int_as_float(__builtin_amdgcn_update_dpp(0, __float_as_int(x), 0x114, 0xf, 0xe, true));
  x += __int_as_float(__builtin_amdgcn_update_dpp(0, __float_as_int(x), 0x118, 0xf, 0xc, true));
  x += __int_as_float(__builtin_amdgcn_update_dpp(0, __float_as_int(x), 0x142, 0xa, 0xf, true));
  x += __int_as_float(__builtin_amdgcn_update_dpp(0, __float_as_int(x), 0x143, 0xc, 0xf, true));
  return __int_as_float(__builtin_amdgcn_readlane(__float_as_int(x), 63));
}

__device__ __forceinline__ float f4sel(float4 a, int cc) {
  float r = (cc == 0) ? a.x : a.y;
  r = (cc == 2) ? a.z : r;
  r = (cc == 3) ? a.w : r;
  return r;
}

__global__ __launch_bounds__(128) void k_tridiag(const float* __restrict__ rho,
                                                 float* __restrict__ dvec_g,
                                                 float* __restrict__ evec_g) {
  extern __shared__ float sm[];
  float4* A4  = (float4*)sm;        // 4096 float4 = 64 KB
  float*  Af  = sm;
  float* cb0  = sm + 16384;         // column ping
  float* cb1  = cb0 + 128;          // column pong
  float* pbuf = cb1 + 128;          // 128
  float* dvl  = pbuf + 128;         // 128
  float* evl  = dvl + 128;          // 128
  float* redS = evl + 128;          // 2
  float* redK = redS + 2;           // 2
  float* redX = redK + 2;           // 1 (+pad)
  const int bb = blockIdx.x, t = threadIdx.x, wv = t >> 6;
  const float* R = rho + bb * 16384;
  for (int f = t; f < 4096; f += 128)
    A4[TSW(f >> 5, f & 31)] = ((const float4*)R)[f];
  __syncthreads();
  // ---- prologue: extract column 0, publish sigma^2 / x0 / diag
  float c = AEL(t, 0);
  cb0[t] = c;
  if (t == 0) dvl[0] = c;
  if (t == 1) redX[0] = c;
  {
    float s2w = dpp_red_sum64((t > 0) ? c * c : 0.f);
    if ((t & 63) == 0) redS[wv] = s2w;
  }
  __syncthreads();
  for (int k = 0; k < 126; ++k) {
    float* cbC = (k & 1) ? cb1 : cb0;   // column k (read)
    float* cbN = (k & 1) ? cb0 : cb1;   // column k+1 (write)
    // ---- uniform head: alpha/beta/w0 from pre-reduced slots
    float sig2 = redS[0] + redS[1];
    float x0 = redX[0];
    const bool skip = (sig2 < 1e-30f);
    float sig = sqrtf(sig2);
    float alpha = (x0 >= 0.f) ? -sig : sig;
    if (skip) alpha = 0.f;
    float beta = skip ? 0.f : 1.f / (sig2 - alpha * x0);
    float w0 = x0 - alpha;
    if (t == 0) evl[k] = alpha;
    const int j4min = (k + 1) >> 2;   // f4 holding column k+1
    const int kc1 = (k + 1) & 3;      // its component
    float cn = 0.f;
    if (!skip) {  // uniform branch
      // v_t (own row's Householder component)
      float vt = (t <= k) ? 0.f : ((t == k + 1) ? w0 : c);
      // ---- matvec p_t = beta * sum_{j>k} A[t][j] v[j]
      float pp = 0.f;
      if (t > k) {
        const float4* c4 = (const float4*)cbC;
        {  // first f4: patch comps (j<k+1 -> 0, j==k+1 -> w0)
          float4 v = c4[j4min];
          v.x = (0 < kc1) ? 0.f : ((0 == kc1) ? w0 : v.x);
          v.y = (1 < kc1) ? 0.f : ((1 == kc1) ? w0 : v.y);
          v.z = (2 < kc1) ? 0.f : ((2 == kc1) ? w0 : v.z);
          v.w = (3 < kc1) ? 0.f : ((3 == kc1) ? w0 : v.w);
          float4 a = A4[TSW(t, j4min)];
          pp += a.x * v.x + a.y * v.y + a.z * v.z + a.w * v.w;
        }
        for (int j4 = j4min + 1; j4 < 32; ++j4) {
          float4 v = c4[j4];
          float4 a = A4[TSW(t, j4)];
          pp += a.x * v.x + a.y * v.y + a.z * v.z + a.w * v.w;
        }
      }
      float p = beta * pp;
      if (t <= k) p = 0.f;
      pbuf[t] = p;
      float kpw = dpp_red_sum64(vt * p);
      if ((t & 63) == 0) redK[wv] = kpw;
      __syncthreads();  // S1: pbuf + redK visible
      float K = (redK[0] + redK[1]) * beta * 0.5f;
      // ---- rank-2 update + extract column k+1 (first f4 of the loop)
      if (t > k) {
        float qt = p - K * vt;
        const float4* c4 = (const float4*)cbC;
        const float4* p4 = (const float4*)pbuf;
        {  // j4 = j4min: patched v, extraction
          float4 v = c4[j4min];
          v.x = (0 < kc1) ? 0.f : ((0 == kc1) ? w0 : v.x);
          v.y = (1 < kc1) ? 0.f : ((1 == kc1) ? w0 : v.y);
          v.z = (2 < kc1) ? 0.f : ((2 == kc1) ? w0 : v.z);
          v.w = (3 < kc1) ? 0.f : ((3 == kc1) ? w0 : v.w);
          float4 pq = p4[j4min];  // comps j<=k already zero (pbuf zeroed)
          float4 q;
          q.x = pq.x - K * v.x; q.y = pq.y - K * v.y;
          q.z = pq.z - K * v.z; q.w = pq.w - K * v.w;
          float4 a = A4[TSW(t, j4min)];
          a.x -= vt * q.x + qt * v.x; a.y -= vt * q.y + qt * v.y;
          a.z -= vt * q.z + qt * v.z; a.w -= vt * q.w + qt * v.w;
          A4[TSW(t, j4min)] = a;
          cn = f4sel(a, kc1);  // new A[t][k+1]
        }
        for (int j4 = j4min + 1; j4 < 32; ++j4) {
          float4 v = c4[j4];
          float4 pq = p4[j4];
          float4 q;
          q.x = pq.x - K * v.x; q.y = pq.y - K * v.y;
          q.z = pq.z - K * v.z; q.w = pq.w - K * v.w;
          float4 a = A4[TSW(t, j4)];
          a.x -= vt * q.x + qt * v.x; a.y -= vt * q.y + qt * v.y;
          a.z -= vt * q.z + qt * v.z; a.w -= vt * q.w + qt * v.w;
          A4[TSW(t, j4)] = a;
        }
      }
    } else {
      // skip: A unchanged; column k+1 read directly
      cn = AEL(t, k + 1);
    }
    // ---- publish next-step state (all lanes active)
    cbN[t] = cn;                       // rows <= k publish 0/stale: never used
    if (t == k + 1) dvl[k + 1] = cn;   // diagonal A[k+1][k+1]
    if (t == k + 2) redX[0] = cn;      // x0 for step k+1
    float s2w = dpp_red_sum64((t > k + 1) ? cn * cn : 0.f);
    if ((t & 63) == 0) redS[wv] = s2w;
    __syncthreads();  // S2: A stable, cbN/slots visible
    c = cn;
  }
  // epilogue: c holds column 126
  if (t == 127) {
    evl[126] = c;                 // A[127][126]
    dvl[127] = AEL(127, 127);
    evl[127] = 0.0f;
  }
  __syncthreads();
  dvec_g[bb * 128 + t] = dvl[t];
  evec_g[bb * 128 + t] = evl[t];
}

// ============================ K8: bisection eigenvalues + normalize ============================
__global__ __launch_bounds__(128) void k_bisect(const float* __restrict__ dvec_g,
                                                const float* __restrict__ evec_g,
                                                float* __restrict__ dist_out) {
  const int bb = blockIdx.x, t = threadIdx.x;
  __shared__ float ds[128], e2s[128], eabs[128];
  __shared__ float rr[2];
  ds[t] = dvec_g[bb * 128 + t];
  float e = evec_g[bb * 128 + t];
  e2s[t] = e * e;
  eabs[t] = fabsf(e);
  __syncthreads();
  float lo = 1e30f, hi = -1e30f;
  for (int ii = 0; ii < 128; ++ii) {
    float r = (ii > 0 ? eabs[ii - 1] : 0.0f) + (ii < 127 ? eabs[ii] : 0.0f);
    lo = fminf(lo, ds[ii] - r);
    hi = fmaxf(hi, ds[ii] + r);
  }
  for (int it = 0; it < 40; ++it) {
    float mid = 0.5f * (lo + hi);
    int cnt = 0;
    float q = ds[0] - mid;
    if (q < 0.0f) cnt++;
    for (int ii = 1; ii < 128; ++ii) {
      float denom = q;
      if (fabsf(denom) < 1e-25f) denom = (denom < 0.0f) ? -1e-25f : 1e-25f;
      q = (ds[ii] - mid) - __fdividef(e2s[ii - 1], denom);
      if (q < 0.0f) cnt++;
    }
    if (cnt <= t) lo = mid; else hi = mid;
  }
  float lam = 0.5f * (lo + hi);
  float evc = fmaxf(lam, 1e-12f);
  float ssum = evc;
  for (int s = 32; s > 0; s >>= 1) ssum += __shfl_xor(ssum, s);
  if ((t & 63) == 0) rr[t >> 6] = ssum;
  __syncthreads();
  float tot = rr[0] + rr[1];
  dist_out[bb * 128 + t] = evc / tot;
}

// ============================ launch ============================
extern "C" void kernel_launch(void* const* d_in, const int* in_sizes, int n_in,
                              void* d_out, int out_size, void* d_ws, size_t ws_size,
                              hipStream_t stream) {
  const float* x      = (const float*)d_in[0];
  const float* L      = (const float*)d_in[1];
  const float* temp_p = (const float*)d_in[2];
  const float* tgt_p  = (const float*)d_in[3];
  const float* step_p = (const float*)d_in[4];
  float* out = (float*)d_out;
  float* ws  = (float*)d_ws;

  float* bases = ws;                    // 2097152
  float* G     = bases + 2097152;       // 16384
  float* w     = G + 16384;             // 16384
  float* s0    = w + 16384;             // 262144
  float* s1    = s0 + 262144;           // 262144
  float* n0    = s1 + 262144;           // 2048
  float* n1    = n0 + 2048;             // 2048
  float* dv    = n1 + 2048;             // 2048
  float* ev    = dv + 2048;             // 2048

  float* o_avg  = out;                  // 2048
  float* o_dist = out + 2048;           // 2048
  float* o_rho  = out + 4096;           // 262144
  float* o_meas = out + 266240;         // 262144
  float* o_eq   = out + 528384;         // 262144
  float* o_expr = out + 790528;         // 262144
  float* o_ten  = out + 1052672;        // 16384

  hipFuncSetAttribute((const void*)k_cayley,
                      hipFuncAttributeMaxDynamicSharedMemorySize, 65536);
  hipFuncSetAttribute((const void*)k_tridiag,
                      hipFuncAttributeMaxDynamicSharedMemorySize, 68224);

  k_cayley<<<128, 512, 65536, stream>>>(L, bases);
  k_gram<<<128, 256, 0, stream>>>(bases, G);
  k_wsoft<<<128, 128, 0, stream>>>(G, temp_p, w, o_ten);
  k_meas<<<128, 128, 0, stream>>>(x, bases, o_meas, s0, n0);
  k_step<<<2048, 128, 0, stream>>>(s0, s1, w, n0, n1, tgt_p, step_p);
  k_step<<<2048, 128, 0, stream>>>(s1, s0, w, n1, n0, tgt_p, step_p);
  k_step<<<2048, 128, 0, stream>>>(s0, s1, w, n0, n1, tgt_p, step_p);
  k_step<<<2048, 128, 0, stream>>>(s1, s0, w, n1, n0, tgt_p, step_p);
  k_step<<<2048, 128, 0, stream>>>(s0, o_eq, w, n0, n1, tgt_p, step_p);
  k_expr<<<128, 128, 0, stream>>>(o_eq, bases, o_expr);
  k_avg<<<16, 128, 0, stream>>>(o_expr, o_avg);
  k_rho<<<128, 256, 0, stream>>>(o_eq, n1, o_rho);
  k_tridiag<<<16, 128, 68224, stream>>>(o_rho, dv, ev);
  k_bisect<<<16, 128, 0, stream>>>(dv, ev, o_dist);
}